// Round 1
// baseline (938.430 us; speedup 1.0000x reference)
//
#include <hip/hip_runtime.h>
#include <hip/hip_bf16.h>
#include <stdint.h>

// ---------------------------------------------------------------------------
// MotionVAE fused kernel: encoder -> z/mu/logvar -> gate softmax -> 4 MoE
// decoder layers. bf16 MFMA (16x16x32), fp32 accumulate.
// ---------------------------------------------------------------------------

#define NB 65536

typedef __attribute__((ext_vector_type(8))) short bf16x8;   // 8 x bf16
typedef __attribute__((ext_vector_type(4))) float f32x4;

union FragU { bf16x8 v; unsigned int w[4]; uint4 u4; };

// ---- workspace byte offsets (packed bf16 weights + blended bias) ----
#define WP_E1   0          // 512x256
#define WP_E2   262144     // 256x256
#define WP_MULV 393216     // 256x128 (mu|lv)
#define WP_G1   458752     // 320x64
#define WP_G2   499712     // 64x64
#define WP_G3   507904     // 64x16 (padded from 64x6)
#define WP_DEC  509952     // 4 layers x 6 experts x 320x256
#define WP_BDEC 4442112    // f32 [4][6][256] blended bias

// ---- LDS byte offsets (60 KiB total) ----
#define L_XIN   0          // 10 chunks x [64][32] bf16 = 40960
#define L_WBUF  40960      // 16384 weight staging / scratch
#define L_MUF   20480      // mu f32 [64][64] (inside XIN, transient)
#define L_LVF   40960      // lv f32 [64][64] (= WBUF, transient)
#define L_HG    49152      // gate hidden chunks (WBUF+8192)
#define L_WG3   49152      // g3 weights (over dead HG)
#define L_SCORE 51200      // gate scores f32 [64][16]
#define L_COEF  57344      // coefT f32 [6][64]
#define L_STATS 58880      // (mean,rstd) f32 [64][2]
#define L_PART  59392      // partial sums f32 [64][4][2]
#define LDS_BYTES 61440

__device__ __forceinline__ unsigned int pack2(float a, float b){
    __hip_bfloat162 h = __float22bfloat162_rn(make_float2(a, b));
    union { __hip_bfloat162 h2; unsigned int u; } cv; cv.h2 = h; return cv.u;
}
__device__ __forceinline__ unsigned short f2bf(float a){
    __hip_bfloat16 h = __float2bfloat16(a);
    union { __hip_bfloat16 h1; unsigned short u; } cv; cv.h1 = h; return cv.u;
}
__device__ __forceinline__ float eluf(float x){ return x > 0.f ? x : expm1f(x); }
__device__ __forceinline__ f32x4 mfma16(bf16x8 a, bf16x8 b, f32x4 c){
    return __builtin_amdgcn_mfma_f32_16x16x32_bf16(a, b, c, 0, 0, 0);
}
// async global->LDS, 16B per lane; lds dest is wave-uniform base (+lane*16 in HW)
__device__ __forceinline__ void gload16(const void* g, void* l){
    __builtin_amdgcn_global_load_lds(
        (__attribute__((address_space(1))) unsigned int*)(uintptr_t)g,
        (__attribute__((address_space(3))) unsigned int*)(unsigned int)(uintptr_t)l,
        16, 0, 0);
}

// ---------------------------------------------------------------------------
// pack kernels: fp32 -> bf16, MFMA-fragment-contiguous layout
// flat = ((kb*(N/16)+ntg)*64 + lane)*8 + i ; element = W[kb*32+(lane>>4)*8+i][ntg*16+(lane&15)]
// ---------------------------------------------------------------------------
__global__ void pack_small(const float* __restrict__ e1w, const float* __restrict__ e2w,
                           const float* __restrict__ muw, const float* __restrict__ lvw,
                           const float* __restrict__ g1w, const float* __restrict__ g2w,
                           const float* __restrict__ g3w, unsigned short* __restrict__ wsh){
    int p = blockIdx.x*256 + threadIdx.x;   // < 254976
    int local, k, n;
    auto decode = [&](int base, int NN){
        local = p - base;
        int i = local & 7, ln = (local>>3)&63, rest = local>>9;
        int ntg = rest % (NN/16), kb = rest / (NN/16);
        k = kb*32 + (ln>>4)*8 + i; n = ntg*16 + (ln&15);
    };
    if (p < 131072)      { decode(0,      256); wsh[WP_E1/2   + local] = f2bf(e1w[k*256+n]); }
    else if (p < 196608) { decode(131072, 256); wsh[WP_E2/2   + local] = f2bf(e2w[k*256+n]); }
    else if (p < 229376) { decode(196608, 128); wsh[WP_MULV/2 + local] = f2bf(n < 64 ? muw[k*64+n] : lvw[k*64+n-64]); }
    else if (p < 249856) { decode(229376,  64); wsh[WP_G1/2   + local] = f2bf(g1w[k*64+n]); }
    else if (p < 253952) { decode(249856,  64); wsh[WP_G2/2   + local] = f2bf(g2w[k*64+n]); }
    else                 { decode(253952,  16); wsh[WP_G3/2   + local] = f2bf(n < 6 ? g3w[k*6+n] : 0.f); }
}

__global__ void pack_dec(const float* __restrict__ w0, const float* __restrict__ w1,
                         const float* __restrict__ w2, const float* __restrict__ w3,
                         const float* __restrict__ s0, const float* __restrict__ s1,
                         const float* __restrict__ s2, const float* __restrict__ s3,
                         unsigned short* __restrict__ wsh){
    int p = blockIdx.x*256 + threadIdx.x;   // < 1966080
    int i = p & 7, ln = (p>>3)&63, rest = p>>9;
    int ntg = rest & 15, r2 = rest >> 4;
    int kb = r2 % 10, r3 = r2 / 10;
    int e = r3 % 6, L = r3 / 6;
    int k = kb*32 + (ln>>4)*8 + i;
    int n = ntg*16 + (ln&15);
    const float* w = (L==0)?w0:(L==1)?w1:(L==2)?w2:w3;
    const float* s = (L==0)?s0:(L==1)?s1:(L==2)?s2:s3;
    wsh[WP_DEC/2 + p] = f2bf(s[k] * w[(e*320+k)*256 + n]);   // fold LN scale
}

__global__ void pack_bdec(const float* __restrict__ w0, const float* __restrict__ w1,
                          const float* __restrict__ w2, const float* __restrict__ w3,
                          const float* __restrict__ b0, const float* __restrict__ b1,
                          const float* __restrict__ b2, const float* __restrict__ b3,
                          const float* __restrict__ t0, const float* __restrict__ t1,
                          const float* __restrict__ t2, const float* __restrict__ t3,
                          float* __restrict__ outp){
    int t = blockIdx.x*256 + threadIdx.x;   // < 6144
    int n = t & 255, r = t >> 8;
    int e = r % 6, L = r / 6;
    const float* w  = (L==0)?w0:(L==1)?w1:(L==2)?w2:w3;
    const float* b  = (L==0)?b0:(L==1)?b1:(L==2)?b2:b3;
    const float* lb = (L==0)?t0:(L==1)?t1:(L==2)?t2:t3;
    float acc = b[e*256 + n];
    for (int k = 0; k < 320; ++k) acc += lb[k] * w[(e*320+k)*256 + n];  // fold LN bias
    outp[(L*6+e)*256 + n] = acc;
}

// ---------------------------------------------------------------------------
// main fused kernel: one block = 64 rows, 4 waves, wave w owns output cols
// [w*64, w*64+64) via 4x16-row x 4x16-col MFMA tiles.
// ---------------------------------------------------------------------------
__global__ __launch_bounds__(256, 2) void vae_main(
    const float* __restrict__ curr, const float* __restrict__ nxt,
    const float* __restrict__ eps,
    const float* __restrict__ eb1, const float* __restrict__ eb2,
    const float* __restrict__ mub, const float* __restrict__ lvb,
    const float* __restrict__ gb1, const float* __restrict__ gb2,
    const float* __restrict__ gb3,
    const unsigned short* __restrict__ wsh, const float* __restrict__ bdec,
    float* __restrict__ dout)
{
    __shared__ __align__(16) char smem[LDS_BYTES];
    const int tid  = threadIdx.x;
    const int lane = tid & 63;
    const int wave = tid >> 6;          // 0..3 = column group
    const int l15  = lane & 15;
    const int lh   = lane >> 4;         // 0..3
    const long row0 = (long)blockIdx.x * 64;
    const char* wsb = (const char*)wsh;
    const f32x4 Z4 = {0.f, 0.f, 0.f, 0.f};

    auto stageW = [&](int srcByte, int nbytes, int ldsOff){
        int nch = nbytes >> 10;
        for (int c = wave; c < nch; c += 4){
            int o = c << 10;
            gload16(wsb + srcByte + o + (lane<<4), smem + ldsOff + o);
        }
    };
    auto loadA = [&](int base, int mt) -> bf16x8 {
        FragU f; f.u4 = *(const uint4*)(smem + base + ((mt*16 + l15)<<6) + (lh<<4));
        return f.v;
    };
    auto loadB = [&](int base, int idx) -> bf16x8 {
        FragU f; f.u4 = *(const uint4*)(smem + base + (idx<<10) + (lane<<4));
        return f.v;
    };

    f32x4 acc4[4][4];
    // ================= encoder layer 1: h1 = elu([curr,next]@W1+b1) =========
    #pragma unroll
    for (int a = 0; a < 4; ++a)
        #pragma unroll
        for (int b = 0; b < 4; ++b) acc4[a][b] = Z4;
    {
        const int xrow = tid >> 2, xg = tid & 3;
        #pragma unroll 1
        for (int kb = 0; kb < 16; ++kb){
            __syncthreads();
            {   // stage X chunk [64][32] bf16 into XIN chunk slot 0
                const float* src = (kb < 8) ? curr : nxt;
                const float* p = src + (row0 + xrow)*256 + (kb & 7)*32 + xg*8;
                float4 fa = *(const float4*)p;
                float4 fb = *(const float4*)(p + 4);
                uint4 pk;
                pk.x = pack2(fa.x, fa.y); pk.y = pack2(fa.z, fa.w);
                pk.z = pack2(fb.x, fb.y); pk.w = pack2(fb.z, fb.w);
                *(uint4*)(smem + L_XIN + (xrow<<6) + (xg<<4)) = pk;
            }
            stageW(WP_E1 + kb*16384, 16384, L_WBUF);
            __syncthreads();
            bf16x8 a[4];
            #pragma unroll
            for (int mt = 0; mt < 4; ++mt) a[mt] = loadA(L_XIN, mt);
            #pragma unroll
            for (int nt = 0; nt < 4; ++nt){
                bf16x8 b = loadB(L_WBUF, wave*4 + nt);
                #pragma unroll
                for (int mt = 0; mt < 4; ++mt) acc4[mt][nt] = mfma16(a[mt], b, acc4[mt][nt]);
            }
        }
        __syncthreads();
        #pragma unroll
        for (int nt = 0; nt < 4; ++nt){
            int n = wave*64 + nt*16 + l15;
            float bias = eb1[n];
            #pragma unroll
            for (int mt = 0; mt < 4; ++mt)
                #pragma unroll
                for (int j = 0; j < 4; ++j){
                    int r = mt*16 + lh*4 + j;
                    float v = eluf(acc4[mt][nt][j] + bias);
                    *(unsigned short*)(smem + L_XIN + ((n>>5)<<12) + (r<<6) + ((n&31)<<1)) = f2bf(v);
                }
        }
        __syncthreads();
    }
    // ================= encoder layer 2: h2 = elu(h1@W2+b2) ==================
    #pragma unroll
    for (int a = 0; a < 4; ++a)
        #pragma unroll
        for (int b = 0; b < 4; ++b) acc4[a][b] = Z4;
    {
        #pragma unroll 1
        for (int kb = 0; kb < 8; ++kb){
            __syncthreads();
            stageW(WP_E2 + kb*16384, 16384, L_WBUF);
            __syncthreads();
            bf16x8 a[4];
            #pragma unroll
            for (int mt = 0; mt < 4; ++mt) a[mt] = loadA(L_XIN + (kb<<12), mt);
            #pragma unroll
            for (int nt = 0; nt < 4; ++nt){
                bf16x8 b = loadB(L_WBUF, wave*4 + nt);
                #pragma unroll
                for (int mt = 0; mt < 4; ++mt) acc4[mt][nt] = mfma16(a[mt], b, acc4[mt][nt]);
            }
        }
        __syncthreads();
        #pragma unroll
        for (int nt = 0; nt < 4; ++nt){
            int n = wave*64 + nt*16 + l15;
            float bias = eb2[n];
            #pragma unroll
            for (int mt = 0; mt < 4; ++mt)
                #pragma unroll
                for (int j = 0; j < 4; ++j){
                    int r = mt*16 + lh*4 + j;
                    float v = eluf(acc4[mt][nt][j] + bias);
                    *(unsigned short*)(smem + L_XIN + ((n>>5)<<12) + (r<<6) + ((n&31)<<1)) = f2bf(v);
                }
        }
        __syncthreads();
    }
    // ================= mu | logvar  (N=128) =================================
    {
        f32x4 am[4][2];
        #pragma unroll
        for (int a = 0; a < 4; ++a){ am[a][0] = Z4; am[a][1] = Z4; }
        #pragma unroll 1
        for (int kb = 0; kb < 8; ++kb){
            __syncthreads();
            stageW(WP_MULV + kb*8192, 8192, L_WBUF);
            __syncthreads();
            bf16x8 a[4];
            #pragma unroll
            for (int mt = 0; mt < 4; ++mt) a[mt] = loadA(L_XIN + (kb<<12), mt);
            #pragma unroll
            for (int nt = 0; nt < 2; ++nt){
                bf16x8 b = loadB(L_WBUF, wave*2 + nt);
                #pragma unroll
                for (int mt = 0; mt < 4; ++mt) am[mt][nt] = mfma16(a[mt], b, am[mt][nt]);
            }
        }
        __syncthreads();
        #pragma unroll
        for (int nt = 0; nt < 2; ++nt){
            int n = wave*32 + nt*16 + l15;
            if (n < 64){
                float bias = mub[n];
                #pragma unroll
                for (int mt = 0; mt < 4; ++mt)
                    #pragma unroll
                    for (int j = 0; j < 4; ++j){
                        int r = mt*16 + lh*4 + j;
                        float v = am[mt][nt][j] + bias;
                        *(float*)(smem + L_MUF + (r<<8) + (n<<2)) = v;
                        dout[(long)NB*320 + (row0 + r)*64 + n] = v;
                    }
            } else {
                float bias = lvb[n-64];
                #pragma unroll
                for (int mt = 0; mt < 4; ++mt)
                    #pragma unroll
                    for (int j = 0; j < 4; ++j){
                        int r = mt*16 + lh*4 + j;
                        float v = am[mt][nt][j] + bias;
                        *(float*)(smem + L_LVF + (r<<8) + ((n-64)<<2)) = v;
                        dout[(long)NB*384 + (row0 + r)*64 + (n-64)] = v;
                    }
            }
        }
        __syncthreads();
    }
    // ================= z = mu + eps*exp(0.5 lv); mu -> bf16 chunks 0,1 ======
    {
        int row = tid >> 2, seg = (tid & 3) * 16;
        float zm[16], zl[16];
        #pragma unroll
        for (int q = 0; q < 4; ++q){
            float4 m4 = *(const float4*)(smem + L_MUF + (row<<8) + ((seg + q*4)<<2));
            float4 l4 = *(const float4*)(smem + L_LVF + (row<<8) + ((seg + q*4)<<2));
            zm[q*4+0]=m4.x; zm[q*4+1]=m4.y; zm[q*4+2]=m4.z; zm[q*4+3]=m4.w;
            zl[q*4+0]=l4.x; zl[q*4+1]=l4.y; zl[q*4+2]=l4.z; zl[q*4+3]=l4.w;
        }
        const float* ep = eps + (row0 + row)*64 + seg;
        float* zo = dout + (long)NB*256 + (row0 + row)*64 + seg;
        #pragma unroll
        for (int q = 0; q < 4; ++q){
            float4 e4 = *(const float4*)(ep + q*4);
            float4 z4;
            z4.x = zm[q*4+0] + e4.x * expf(0.5f*zl[q*4+0]);
            z4.y = zm[q*4+1] + e4.y * expf(0.5f*zl[q*4+1]);
            z4.z = zm[q*4+2] + e4.z * expf(0.5f*zl[q*4+2]);
            z4.w = zm[q*4+3] + e4.w * expf(0.5f*zl[q*4+3]);
            *(float4*)(zo + q*4) = z4;
        }
        uint4 pkA, pkB;
        pkA.x = pack2(zm[0],  zm[1]);  pkA.y = pack2(zm[2],  zm[3]);
        pkA.z = pack2(zm[4],  zm[5]);  pkA.w = pack2(zm[6],  zm[7]);
        pkB.x = pack2(zm[8],  zm[9]);  pkB.y = pack2(zm[10], zm[11]);
        pkB.z = pack2(zm[12], zm[13]); pkB.w = pack2(zm[14], zm[15]);
        char* dst = smem + L_XIN + ((seg>>5)<<12) + (row<<6) + ((seg&31)<<1);
        *(uint4*)dst = pkA;
        *(uint4*)(dst + 16) = pkB;
    }
    __syncthreads();
    // ================= stage curr -> xin chunks 2..9 (bf16) =================
    #pragma unroll
    for (int c = 0; c < 2; ++c){
        int idx = c*256 + tid;
        int row = idx & 63, kbi = idx >> 6;     // 0..7
        const float* p = curr + (row0 + row)*256 + kbi*32;
        #pragma unroll
        for (int g = 0; g < 4; ++g){
            float4 fa = *(const float4*)(p + g*8);
            float4 fb = *(const float4*)(p + g*8 + 4);
            uint4 pk;
            pk.x = pack2(fa.x, fa.y); pk.y = pack2(fa.z, fa.w);
            pk.z = pack2(fb.x, fb.y); pk.w = pack2(fb.z, fb.w);
            *(uint4*)(smem + L_XIN + ((2+kbi)<<12) + (row<<6) + (g<<4)) = pk;
        }
    }
    __syncthreads();
    // ================= gating MLP ===========================================
    {
        f32x4 ga[4];
        #pragma unroll
        for (int a = 0; a < 4; ++a) ga[a] = Z4;
        #pragma unroll 1
        for (int kb = 0; kb < 10; ++kb){
            __syncthreads();
            stageW(WP_G1 + kb*4096, 4096, L_WBUF);
            __syncthreads();
            bf16x8 b = loadB(L_WBUF, wave);
            #pragma unroll
            for (int mt = 0; mt < 4; ++mt) ga[mt] = mfma16(loadA(L_XIN + (kb<<12), mt), b, ga[mt]);
        }
        __syncthreads();
        {
            int n = wave*16 + l15;
            float bias = gb1[n];
            #pragma unroll
            for (int mt = 0; mt < 4; ++mt)
                #pragma unroll
                for (int j = 0; j < 4; ++j){
                    int r = mt*16 + lh*4 + j;
                    float v = eluf(ga[mt][j] + bias);
                    *(unsigned short*)(smem + L_HG + ((n>>5)<<12) + (r<<6) + ((n&31)<<1)) = f2bf(v);
                }
        }
        __syncthreads();
        // G2
        stageW(WP_G2, 8192, L_WBUF);
        __syncthreads();
        #pragma unroll
        for (int a = 0; a < 4; ++a) ga[a] = Z4;
        #pragma unroll
        for (int kb = 0; kb < 2; ++kb){
            bf16x8 b = loadB(L_WBUF, kb*4 + wave);
            #pragma unroll
            for (int mt = 0; mt < 4; ++mt) ga[mt] = mfma16(loadA(L_HG + (kb<<12), mt), b, ga[mt]);
        }
        __syncthreads();
        {
            int n = wave*16 + l15;
            float bias = gb2[n];
            #pragma unroll
            for (int mt = 0; mt < 4; ++mt)
                #pragma unroll
                for (int j = 0; j < 4; ++j){
                    int r = mt*16 + lh*4 + j;
                    float v = eluf(ga[mt][j] + bias);
                    *(unsigned short*)(smem + L_WBUF + ((n>>5)<<12) + (r<<6) + ((n&31)<<1)) = f2bf(v);
                }
        }
        __syncthreads();
        // G3 (N=16, wave 0 computes)
        if (wave < 2)
            gload16(wsb + WP_G3 + wave*1024 + (lane<<4), smem + L_WG3 + wave*1024);
        __syncthreads();
        if (wave == 0){
            f32x4 sc[4];
            #pragma unroll
            for (int a = 0; a < 4; ++a) sc[a] = Z4;
            #pragma unroll
            for (int kb = 0; kb < 2; ++kb){
                bf16x8 b = loadB(L_WG3, kb);
                #pragma unroll
                for (int mt = 0; mt < 4; ++mt) sc[mt] = mfma16(loadA(L_WBUF + (kb<<12), mt), b, sc[mt]);
            }
            float bias = (l15 < 6) ? gb3[l15] : 0.f;
            #pragma unroll
            for (int mt = 0; mt < 4; ++mt)
                #pragma unroll
                for (int j = 0; j < 4; ++j){
                    int r = mt*16 + lh*4 + j;
                    *(float*)(smem + L_SCORE + (r<<6) + (l15<<2)) = sc[mt][j] + bias;
                }
        }
        __syncthreads();
        if (tid < 64){
            float s[6];
            #pragma unroll
            for (int e = 0; e < 6; ++e) s[e] = *(const float*)(smem + L_SCORE + (tid<<6) + (e<<2));
            float m = s[0];
            #pragma unroll
            for (int e = 1; e < 6; ++e) m = fmaxf(m, s[e]);
            float sum = 0.f;
            #pragma unroll
            for (int e = 0; e < 6; ++e){ s[e] = expf(s[e] - m); sum += s[e]; }
            float inv = 1.f / sum;
            #pragma unroll
            for (int e = 0; e < 6; ++e) *(float*)(smem + L_COEF + ((e*64 + tid)<<2)) = s[e]*inv;
        }
        __syncthreads();
    }
    // ================= decoder: 4 MoE layers ================================
    f32x4 resid[4][4];
    #pragma unroll 1
    for (int L = 0; L < 4; ++L){
        // ---- LN stats over the 320 raw bf16 values per row ----
        {
            int row = tid >> 2, part = tid & 3;
            float s = 0.f, sq = 0.f;
            #pragma unroll
            for (int q = 0; q < 10; ++q){
                int gall = part + q*4;
                uint4 d = *(const uint4*)(smem + L_XIN + ((gall>>2)<<12) + (row<<6) + ((gall&3)<<4));
                unsigned int wv[4] = {d.x, d.y, d.z, d.w};
                #pragma unroll
                for (int u = 0; u < 4; ++u){
                    float lo = __uint_as_float(wv[u] << 16);
                    float hi = __uint_as_float(wv[u] & 0xffff0000u);
                    s += lo + hi; sq += lo*lo + hi*hi;
                }
            }
            *(float2*)(smem + L_PART + ((row*4 + part)<<3)) = make_float2(s, sq);
        }
        __syncthreads();
        if (tid < 64){
            float S = 0.f, Q = 0.f;
            #pragma unroll
            for (int pp = 0; pp < 4; ++pp){
                float2 f = *(const float2*)(smem + L_PART + ((tid*4 + pp)<<3));
                S += f.x; Q += f.y;
            }
            float mean = S * (1.f/320.f);
            float var  = Q * (1.f/320.f) - mean*mean;
            *(float2*)(smem + L_STATS + (tid<<3)) = make_float2(mean, rsqrtf(var + 1e-5f));
        }
        __syncthreads();

        float meanA[4], rstdA[4];
        #pragma unroll
        for (int mt = 0; mt < 4; ++mt){
            float2 st = *(const float2*)(smem + L_STATS + ((mt*16 + l15)<<3));
            meanA[mt] = st.x; rstdA[mt] = st.y;
        }

        f32x4 acc[4][4];
        #pragma unroll
        for (int a = 0; a < 4; ++a)
            #pragma unroll
            for (int b = 0; b < 4; ++b) acc[a][b] = Z4;

        #pragma unroll 1
        for (int e = 0; e < 6; ++e){
            float al[4], be[4];
            #pragma unroll
            for (int mt = 0; mt < 4; ++mt){
                float c = *(const float*)(smem + L_COEF + ((e*64 + mt*16 + l15)<<2));
                al[mt] = c * rstdA[mt];
                be[mt] = -meanA[mt] * al[mt];
            }
            #pragma unroll 1
            for (int kb = 0; kb < 10; ++kb){
                __syncthreads();
                stageW(WP_DEC + ((L*6 + e)*10 + kb)*16384, 16384, L_WBUF);
                __syncthreads();
                FragU a[4];
                #pragma unroll
                for (int mt = 0; mt < 4; ++mt){
                    a[mt].u4 = *(const uint4*)(smem + L_XIN + (kb<<12) + ((mt*16 + l15)<<6) + (lh<<4));
                    #pragma unroll
                    for (int q = 0; q < 4; ++q){   // a' = bf16(coef * (x-mean)*rstd)
                        unsigned int w = a[mt].w[q];
                        float lo = __uint_as_float(w << 16)         * al[mt] + be[mt];
                        float hi = __uint_as_float(w & 0xffff0000u) * al[mt] + be[mt];
                        a[mt].w[q] = pack2(lo, hi);
                    }
                }
                #pragma unroll
                for (int nt = 0; nt < 4; ++nt){
                    FragU b; b.u4 = *(const uint4*)(smem + L_WBUF + (((wave*4 + nt)*64 + lane)<<4));
                    #pragma unroll
                    for (int mt = 0; mt < 4; ++mt) acc[mt][nt] = mfma16(a[mt].v, b.v, acc[mt][nt]);
                }
            }
        }
        __syncthreads();

        // ---- epilogue: + blended bias, residual/ELU, write back ----
        float bv[6][4];
        #pragma unroll
        for (int e = 0; e < 6; ++e)
            #pragma unroll
            for (int nt = 0; nt < 4; ++nt)
                bv[e][nt] = bdec[((L*6 + e)<<8) + wave*64 + nt*16 + l15];

        #pragma unroll
        for (int mt = 0; mt < 4; ++mt){
            f32x4 cq[6];
            #pragma unroll
            for (int e = 0; e < 6; ++e)
                cq[e] = *(const f32x4*)(smem + L_COEF + ((e*64 + mt*16 + lh*4)<<2));
            #pragma unroll
            for (int nt = 0; nt < 4; ++nt){
                int n = wave*64 + nt*16 + l15;
                f32x4 v;
                #pragma unroll
                for (int j = 0; j < 4; ++j){
                    float bias = cq[0][j]*bv[0][nt] + cq[1][j]*bv[1][nt] + cq[2][j]*bv[2][nt]
                               + cq[3][j]*bv[3][nt] + cq[4][j]*bv[4][nt] + cq[5][j]*bv[5][nt];
                    float mix = acc[mt][nt][j] + bias;
                    float o;
                    if (L == 0)      o = eluf(mix);
                    else if (L < 3)  o = eluf(resid[mt][nt][j] + mix);
                    else             o = mix;
                    v[j] = o;
                }
                if (L < 3){
                    resid[mt][nt] = v;
                    int k = 64 + n;
                    #pragma unroll
                    for (int j = 0; j < 4; ++j){
                        int r = mt*16 + lh*4 + j;
                        *(unsigned short*)(smem + L_XIN + ((k>>5)<<12) + (r<<6) + ((k&31)<<1)) = f2bf(v[j]);
                    }
                } else {
                    #pragma unroll
                    for (int j = 0; j < 4; ++j){
                        int r = mt*16 + lh*4 + j;
                        dout[(row0 + r)*256 + n] = v[j];
                    }
                }
            }
        }
        __syncthreads();
    }
}

// ---------------------------------------------------------------------------
extern "C" void kernel_launch(void* const* d_in, const int* in_sizes, int n_in,
                              void* d_out, int out_size, void* d_ws, size_t ws_size,
                              hipStream_t stream)
{
    (void)in_sizes; (void)n_in; (void)out_size; (void)ws_size;
    const float* curr = (const float*)d_in[0];
    const float* nxt  = (const float*)d_in[1];
    const float* eps  = (const float*)d_in[2];
    const float* ew1  = (const float*)d_in[3];
    const float* eb1  = (const float*)d_in[4];
    const float* ew2  = (const float*)d_in[5];
    const float* eb2  = (const float*)d_in[6];
    const float* muw  = (const float*)d_in[7];
    const float* mub  = (const float*)d_in[8];
    const float* lvw  = (const float*)d_in[9];
    const float* lvb  = (const float*)d_in[10];
    const float* gw1  = (const float*)d_in[11];
    const float* gb1  = (const float*)d_in[12];
    const float* gw2  = (const float*)d_in[13];
    const float* gb2  = (const float*)d_in[14];
    const float* gw3  = (const float*)d_in[15];
    const float* gb3  = (const float*)d_in[16];
    const float* w0 = (const float*)d_in[17]; const float* b0 = (const float*)d_in[18];
    const float* s0 = (const float*)d_in[19]; const float* t0 = (const float*)d_in[20];
    const float* w1 = (const float*)d_in[21]; const float* b1 = (const float*)d_in[22];
    const float* s1 = (const float*)d_in[23]; const float* t1 = (const float*)d_in[24];
    const float* w2 = (const float*)d_in[25]; const float* b2 = (const float*)d_in[26];
    const float* s2 = (const float*)d_in[27]; const float* t2 = (const float*)d_in[28];
    const float* w3 = (const float*)d_in[29]; const float* b3 = (const float*)d_in[30];
    const float* s3 = (const float*)d_in[31]; const float* t3 = (const float*)d_in[32];

    unsigned short* wsh = (unsigned short*)d_ws;
    float* bdec = (float*)((char*)d_ws + WP_BDEC);
    float* dout = (float*)d_out;

    hipLaunchKernelGGL(pack_small, dim3(996), dim3(256), 0, stream,
                       ew1, ew2, muw, lvw, gw1, gw2, gw3, wsh);
    hipLaunchKernelGGL(pack_dec, dim3(7680), dim3(256), 0, stream,
                       w0, w1, w2, w3, s0, s1, s2, s3, wsh);
    hipLaunchKernelGGL(pack_bdec, dim3(24), dim3(256), 0, stream,
                       w0, w1, w2, w3, b0, b1, b2, b3, t0, t1, t2, t3, bdec);
    hipLaunchKernelGGL(vae_main, dim3(1024), dim3(256), 0, stream,
                       curr, nxt, eps, eb1, eb2, mub, lvb, gb1, gb2, gb3,
                       wsh, bdec, dout);
}

// Round 2
// 687.888 us; speedup vs baseline: 1.3642x; 1.3642x over previous
//
#include <hip/hip_runtime.h>
#include <hip/hip_bf16.h>
#include <stdint.h>

// ---------------------------------------------------------------------------
// MotionVAE fused kernel, round 2: 128-row blocks (512 thr, 8 waves),
// XOR-swizzled LDS activation tiles, double-buffered weight staging,
// decoder with A-in-registers reused across 6 experts, MFMA accumulating
// straight into a residual-carrying master accumulator.
// ---------------------------------------------------------------------------

#define NB 65536
#define CHUNK 8192   // one activation chunk: [128 rows][32 bf16 cols] = 8 KiB

typedef __attribute__((ext_vector_type(8))) short bf16x8;   // 8 x bf16
typedef __attribute__((ext_vector_type(4))) float f32x4;

union FragU { bf16x8 v; unsigned int w[4]; uint4 u4; };

// ---- workspace byte offsets (packed bf16 weights + blended bias) ----
#define WP_E1   0          // 512x256
#define WP_E2   262144     // 256x256
#define WP_MULV 393216     // 256x128 (mu|lv)
#define WP_G1   458752     // 320x64
#define WP_G2   499712     // 64x64
#define WP_G3   507904     // 64x16 (padded from 64x6)
#define WP_DEC  509952     // 4 layers x 6 experts x 320x256
#define WP_BDEC 4442112    // f32 [4][6][256] blended bias

// ---- LDS byte offsets (128 KiB total) ----
#define L_XIN   0                  // 10 chunks x 8192 = 81920
#define L_WB0   81920              // weight staging buffer 0 (16 KiB)
#define L_WB1   98304              // weight staging buffer 1 (16 KiB)
#define L_HG    114688             // gate hidden h1 (2 chunks, 16 KiB)
#define L_HG2   L_WB1              // gate hidden h2 overlay (2 chunks)
#define L_SCORE L_HG               // gate scores f32 [128][16] (8 KiB, HG dead)
#define L_COEF  (L_HG + 8192)      // coefT f32 [6][128] = 3072
#define L_STATS (L_HG + 11264)     // (mean,rstd) f32 [128][2] = 1024
#define L_PART  (L_HG + 12288)     // partial sums f32 [128][4][2] = 4096
#define L_MUF   (L_XIN + 2*CHUNK)  // mu f32 [128][64] overlay (32 KiB, transient)
#define L_LVF   L_WB0              // lv f32 [128][64] overlay (32 KiB, transient)
#define LDS_BYTES 131072

__device__ __forceinline__ unsigned int pack2(float a, float b){
    __hip_bfloat162 h = __float22bfloat162_rn(make_float2(a, b));
    union { __hip_bfloat162 h2; unsigned int u; } cv; cv.h2 = h; return cv.u;
}
__device__ __forceinline__ unsigned short f2bf(float a){
    __hip_bfloat16 h = __float2bfloat16(a);
    union { __hip_bfloat16 h1; unsigned short u; } cv; cv.h1 = h; return cv.u;
}
__device__ __forceinline__ float eluf(float x){ return x > 0.f ? x : expm1f(x); }
__device__ __forceinline__ f32x4 mfma16(bf16x8 a, bf16x8 b, f32x4 c){
    return __builtin_amdgcn_mfma_f32_16x16x32_bf16(a, b, c, 0, 0, 0);
}
__device__ __forceinline__ void gload16(const void* g, void* l){
    __builtin_amdgcn_global_load_lds(
        (__attribute__((address_space(1))) unsigned int*)(uintptr_t)g,
        (__attribute__((address_space(3))) unsigned int*)(unsigned int)(uintptr_t)l,
        16, 0, 0);
}

// ---------------------------------------------------------------------------
// pack kernels (unchanged from round 1): fp32 -> bf16, MFMA-fragment layout
// flat = ((kb*(N/16)+ntg)*64 + lane)*8 + i ;
// element = W[kb*32+(lane>>4)*8+i][ntg*16+(lane&15)]
// ---------------------------------------------------------------------------
__global__ void pack_small(const float* __restrict__ e1w, const float* __restrict__ e2w,
                           const float* __restrict__ muw, const float* __restrict__ lvw,
                           const float* __restrict__ g1w, const float* __restrict__ g2w,
                           const float* __restrict__ g3w, unsigned short* __restrict__ wsh){
    int p = blockIdx.x*256 + threadIdx.x;   // < 254976
    int local, k, n;
    auto decode = [&](int base, int NN){
        local = p - base;
        int i = local & 7, ln = (local>>3)&63, rest = local>>9;
        int ntg = rest % (NN/16), kb = rest / (NN/16);
        k = kb*32 + (ln>>4)*8 + i; n = ntg*16 + (ln&15);
    };
    if (p < 131072)      { decode(0,      256); wsh[WP_E1/2   + local] = f2bf(e1w[k*256+n]); }
    else if (p < 196608) { decode(131072, 256); wsh[WP_E2/2   + local] = f2bf(e2w[k*256+n]); }
    else if (p < 229376) { decode(196608, 128); wsh[WP_MULV/2 + local] = f2bf(n < 64 ? muw[k*64+n] : lvw[k*64+n-64]); }
    else if (p < 249856) { decode(229376,  64); wsh[WP_G1/2   + local] = f2bf(g1w[k*64+n]); }
    else if (p < 253952) { decode(249856,  64); wsh[WP_G2/2   + local] = f2bf(g2w[k*64+n]); }
    else                 { decode(253952,  16); wsh[WP_G3/2   + local] = f2bf(n < 6 ? g3w[k*6+n] : 0.f); }
}

__global__ void pack_dec(const float* __restrict__ w0, const float* __restrict__ w1,
                         const float* __restrict__ w2, const float* __restrict__ w3,
                         const float* __restrict__ s0, const float* __restrict__ s1,
                         const float* __restrict__ s2, const float* __restrict__ s3,
                         unsigned short* __restrict__ wsh){
    int p = blockIdx.x*256 + threadIdx.x;   // < 1966080
    int i = p & 7, ln = (p>>3)&63, rest = p>>9;
    int ntg = rest & 15, r2 = rest >> 4;
    int kb = r2 % 10, r3 = r2 / 10;
    int e = r3 % 6, L = r3 / 6;
    int k = kb*32 + (ln>>4)*8 + i;
    int n = ntg*16 + (ln&15);
    const float* w = (L==0)?w0:(L==1)?w1:(L==2)?w2:w3;
    const float* s = (L==0)?s0:(L==1)?s1:(L==2)?s2:s3;
    wsh[WP_DEC/2 + p] = f2bf(s[k] * w[(e*320+k)*256 + n]);   // fold LN scale
}

__global__ void pack_bdec(const float* __restrict__ w0, const float* __restrict__ w1,
                          const float* __restrict__ w2, const float* __restrict__ w3,
                          const float* __restrict__ b0, const float* __restrict__ b1,
                          const float* __restrict__ b2, const float* __restrict__ b3,
                          const float* __restrict__ t0, const float* __restrict__ t1,
                          const float* __restrict__ t2, const float* __restrict__ t3,
                          float* __restrict__ outp){
    int t = blockIdx.x*256 + threadIdx.x;   // < 6144
    int n = t & 255, r = t >> 8;
    int e = r % 6, L = r / 6;
    const float* w  = (L==0)?w0:(L==1)?w1:(L==2)?w2:w3;
    const float* b  = (L==0)?b0:(L==1)?b1:(L==2)?b2:b3;
    const float* lb = (L==0)?t0:(L==1)?t1:(L==2)?t2:t3;
    float acc = b[e*256 + n];
    for (int k = 0; k < 320; ++k) acc += lb[k] * w[(e*320+k)*256 + n];  // fold LN bias
    outp[(L*6+e)*256 + n] = acc;
}

// ---------------------------------------------------------------------------
// main fused kernel: 512 blocks x 512 threads; block = 128 rows; wave grid
// 2 (rows) x 4 (cols); each wave owns a 64x64 output tile (4x4 MFMA frags).
// ---------------------------------------------------------------------------
__global__ __launch_bounds__(512, 2) void vae_main(
    const float* __restrict__ curr, const float* __restrict__ nxt,
    const float* __restrict__ eps,
    const float* __restrict__ eb1, const float* __restrict__ eb2,
    const float* __restrict__ mub, const float* __restrict__ lvb,
    const float* __restrict__ gb1, const float* __restrict__ gb2,
    const float* __restrict__ gb3,
    const unsigned short* __restrict__ wsh, const float* __restrict__ bdec,
    float* __restrict__ dout)
{
    __shared__ __align__(16) char sm[LDS_BYTES];
    const int tid  = threadIdx.x;
    const int lane = tid & 63;
    const int wave = tid >> 6;          // 0..7
    const int wr   = wave >> 2;         // row half
    const int wc   = wave & 3;          // column group
    const int l15  = lane & 15;
    const int lh   = lane >> 4;         // 0..3
    const long row0 = (long)blockIdx.x * 128;
    const char* wsb = (const char*)wsh;
    const f32x4 Z4 = {0.f, 0.f, 0.f, 0.f};

    // A-fragment byte offset within a chunk, XOR-swizzled:
    // element (row, col) lives at row*64 + (((col>>3) ^ ((row>>1)&3))<<4) + (col&7)*2
    const int aswz = ((lh ^ ((l15 >> 1) & 3)) << 4);
    int aoff[4];
    #pragma unroll
    for (int mt = 0; mt < 4; ++mt)
        aoff[mt] = ((((wr << 6) + (mt << 4) + l15)) << 6) + aswz;

    auto stageChunks = [&](long gOff, int nch, int ldsBase){
        for (int c = wave; c < nch; c += 8)
            gload16(wsb + gOff + ((long)c << 10) + (lane << 4), sm + ldsBase + (c << 10));
    };
    auto loadB = [&](int bufBase, int idx) -> bf16x8 {
        FragU f; f.u4 = *(const uint4*)(sm + bufBase + (idx << 10) + (lane << 4));
        return f.v;
    };
    // scatter one f32x4 (4 consecutive rows of one column) to a swizzled tile
    auto putRow = [&](int base, int n, int mt, const f32x4& v){
        char* cb = sm + base + ((n >> 5) * CHUNK);
        int col = n & 31;
        #pragma unroll
        for (int j = 0; j < 4; ++j){
            int r = (wr << 6) + (mt << 4) + (lh << 2) + j;
            *(unsigned short*)(cb + (r << 6) + ((((col >> 3) ^ ((r >> 1) & 3))) << 4)
                               + ((col & 7) << 1)) = f2bf(v[j]);
        }
    };

    f32x4 acc4[4][4];
    // ================= encoder layer 1: h1 = elu([curr,next]@W1+b1) =========
    #pragma unroll
    for (int a = 0; a < 4; ++a)
        #pragma unroll
        for (int b = 0; b < 4; ++b) acc4[a][b] = Z4;
    {
        auto packX = [&](int kb, int slot){
            int row = tid >> 2, g = tid & 3;
            const float* src = (kb < 8) ? curr : nxt;
            const float* p = src + (row0 + row)*256 + (kb & 7)*32 + g*8;
            float4 fa = *(const float4*)p;
            float4 fb = *(const float4*)(p + 4);
            uint4 pk;
            pk.x = pack2(fa.x, fa.y); pk.y = pack2(fa.z, fa.w);
            pk.z = pack2(fb.x, fb.y); pk.w = pack2(fb.z, fb.w);
            *(uint4*)(sm + L_XIN + slot*CHUNK + (row << 6)
                      + ((g ^ ((row >> 1) & 3)) << 4)) = pk;
        };
        packX(0, 0);
        stageChunks(WP_E1, 16, L_WB0);
        __syncthreads();
        #pragma unroll 1
        for (int kb = 0; kb < 16; ++kb){
            if (kb < 15){
                packX(kb + 1, (kb + 1) & 1);
                stageChunks(WP_E1 + (long)(kb + 1)*16384, 16, ((kb + 1) & 1) ? L_WB1 : L_WB0);
            }
            int xb = L_XIN + (kb & 1)*CHUNK;
            int wb = (kb & 1) ? L_WB1 : L_WB0;
            FragU a[4];
            #pragma unroll
            for (int mt = 0; mt < 4; ++mt) a[mt].u4 = *(const uint4*)(sm + xb + aoff[mt]);
            #pragma unroll
            for (int nt = 0; nt < 4; ++nt){
                bf16x8 b = loadB(wb, wc*4 + nt);
                #pragma unroll
                for (int mt = 0; mt < 4; ++mt) acc4[mt][nt] = mfma16(a[mt].v, b, acc4[mt][nt]);
            }
            __syncthreads();
        }
        #pragma unroll
        for (int nt = 0; nt < 4; ++nt){
            int n = wc*64 + nt*16 + l15;
            float bias = eb1[n];
            #pragma unroll
            for (int mt = 0; mt < 4; ++mt){
                f32x4 v;
                #pragma unroll
                for (int j = 0; j < 4; ++j) v[j] = eluf(acc4[mt][nt][j] + bias);
                putRow(L_XIN, n, mt, v);
            }
        }
        __syncthreads();
    }
    // ================= encoder layer 2: h2 = elu(h1@W2+b2) ==================
    #pragma unroll
    for (int a = 0; a < 4; ++a)
        #pragma unroll
        for (int b = 0; b < 4; ++b) acc4[a][b] = Z4;
    {
        stageChunks(WP_E2, 16, L_WB0);
        __syncthreads();
        #pragma unroll 1
        for (int kb = 0; kb < 8; ++kb){
            if (kb < 7)
                stageChunks(WP_E2 + (long)(kb + 1)*16384, 16, ((kb + 1) & 1) ? L_WB1 : L_WB0);
            int wb = (kb & 1) ? L_WB1 : L_WB0;
            FragU a[4];
            #pragma unroll
            for (int mt = 0; mt < 4; ++mt)
                a[mt].u4 = *(const uint4*)(sm + L_XIN + kb*CHUNK + aoff[mt]);
            #pragma unroll
            for (int nt = 0; nt < 4; ++nt){
                bf16x8 b = loadB(wb, wc*4 + nt);
                #pragma unroll
                for (int mt = 0; mt < 4; ++mt) acc4[mt][nt] = mfma16(a[mt].v, b, acc4[mt][nt]);
            }
            __syncthreads();
        }
        #pragma unroll
        for (int nt = 0; nt < 4; ++nt){
            int n = wc*64 + nt*16 + l15;
            float bias = eb2[n];
            #pragma unroll
            for (int mt = 0; mt < 4; ++mt){
                f32x4 v;
                #pragma unroll
                for (int j = 0; j < 4; ++j) v[j] = eluf(acc4[mt][nt][j] + bias);
                putRow(L_XIN, n, mt, v);
            }
        }
        __syncthreads();
    }
    // ================= mu | logvar  (N=128) =================================
    {
        f32x4 am[4][2];
        #pragma unroll
        for (int a = 0; a < 4; ++a){ am[a][0] = Z4; am[a][1] = Z4; }
        stageChunks(WP_MULV, 8, L_WB0);
        __syncthreads();
        #pragma unroll 1
        for (int kb = 0; kb < 8; ++kb){
            if (kb < 7)
                stageChunks(WP_MULV + (long)(kb + 1)*8192, 8, ((kb + 1) & 1) ? L_WB1 : L_WB0);
            int wb = (kb & 1) ? L_WB1 : L_WB0;
            FragU a[4];
            #pragma unroll
            for (int mt = 0; mt < 4; ++mt)
                a[mt].u4 = *(const uint4*)(sm + L_XIN + kb*CHUNK + aoff[mt]);
            #pragma unroll
            for (int nt = 0; nt < 2; ++nt){
                bf16x8 b = loadB(wb, wc*2 + nt);
                #pragma unroll
                for (int mt = 0; mt < 4; ++mt) am[mt][nt] = mfma16(a[mt].v, b, am[mt][nt]);
            }
            __syncthreads();
        }
        #pragma unroll
        for (int nt = 0; nt < 2; ++nt){
            int n = wc*32 + nt*16 + l15;    // 0..127
            if (n < 64){
                float bias = mub[n];
                #pragma unroll
                for (int mt = 0; mt < 4; ++mt)
                    #pragma unroll
                    for (int j = 0; j < 4; ++j){
                        int r = (wr << 6) + (mt << 4) + (lh << 2) + j;
                        float v = am[mt][nt][j] + bias;
                        *(float*)(sm + L_MUF + (r << 8) + (n << 2)) = v;
                        dout[(long)NB*320 + (row0 + r)*64 + n] = v;
                    }
            } else {
                float bias = lvb[n - 64];
                #pragma unroll
                for (int mt = 0; mt < 4; ++mt)
                    #pragma unroll
                    for (int j = 0; j < 4; ++j){
                        int r = (wr << 6) + (mt << 4) + (lh << 2) + j;
                        float v = am[mt][nt][j] + bias;
                        *(float*)(sm + L_LVF + (r << 8) + ((n - 64) << 2)) = v;
                        dout[(long)NB*384 + (row0 + r)*64 + (n - 64)] = v;
                    }
            }
        }
        __syncthreads();
    }
    // ======= z = mu + eps*exp(0.5 lv);  mu (bf16) -> chunks 0,1 =============
    {
        int row = tid >> 2, seg = (tid & 3) << 4;
        float zm[16], zl[16];
        #pragma unroll
        for (int q = 0; q < 4; ++q){
            float4 m4 = *(const float4*)(sm + L_MUF + (row << 8) + ((seg + q*4) << 2));
            float4 l4 = *(const float4*)(sm + L_LVF + (row << 8) + ((seg + q*4) << 2));
            zm[q*4+0]=m4.x; zm[q*4+1]=m4.y; zm[q*4+2]=m4.z; zm[q*4+3]=m4.w;
            zl[q*4+0]=l4.x; zl[q*4+1]=l4.y; zl[q*4+2]=l4.z; zl[q*4+3]=l4.w;
        }
        const float* ep = eps + (row0 + row)*64 + seg;
        float* zo = dout + (long)NB*256 + (row0 + row)*64 + seg;
        #pragma unroll
        for (int q = 0; q < 4; ++q){
            float4 e4 = *(const float4*)(ep + q*4);
            float4 z4;
            z4.x = zm[q*4+0] + e4.x * expf(0.5f*zl[q*4+0]);
            z4.y = zm[q*4+1] + e4.y * expf(0.5f*zl[q*4+1]);
            z4.z = zm[q*4+2] + e4.z * expf(0.5f*zl[q*4+2]);
            z4.w = zm[q*4+3] + e4.w * expf(0.5f*zl[q*4+3]);
            *(float4*)(zo + q*4) = z4;
        }
        uint4 pkA, pkB;
        pkA.x = pack2(zm[0],  zm[1]);  pkA.y = pack2(zm[2],  zm[3]);
        pkA.z = pack2(zm[4],  zm[5]);  pkA.w = pack2(zm[6],  zm[7]);
        pkB.x = pack2(zm[8],  zm[9]);  pkB.y = pack2(zm[10], zm[11]);
        pkB.z = pack2(zm[12], zm[13]); pkB.w = pack2(zm[14], zm[15]);
        int c = seg >> 5, g0 = (seg & 31) >> 3, sw = (row >> 1) & 3;
        char* cb = sm + L_XIN + c*CHUNK + (row << 6);
        *(uint4*)(cb + ((g0 ^ sw) << 4))       = pkA;
        *(uint4*)(cb + (((g0 + 1) ^ sw) << 4)) = pkB;
    }
    __syncthreads();
    // ================= stage curr -> chunks 2..9 (bf16, swizzled) ==========
    #pragma unroll
    for (int c = 0; c < 2; ++c){
        int idx = c*512 + tid;
        int row = idx & 127, kbi = idx >> 7;     // 0..7
        const float* p = curr + (row0 + row)*256 + kbi*32;
        char* cb = sm + L_XIN + (2 + kbi)*CHUNK + (row << 6);
        int sw = (row >> 1) & 3;
        #pragma unroll
        for (int g = 0; g < 4; ++g){
            float4 fa = *(const float4*)(p + g*8);
            float4 fb = *(const float4*)(p + g*8 + 4);
            uint4 pk;
            pk.x = pack2(fa.x, fa.y); pk.y = pack2(fa.z, fa.w);
            pk.z = pack2(fb.x, fb.y); pk.w = pack2(fb.z, fb.w);
            *(uint4*)(cb + ((g ^ sw) << 4)) = pk;
        }
    }
    __syncthreads();
    // ================= gating MLP ===========================================
    {
        f32x4 ga[4];
        #pragma unroll
        for (int a = 0; a < 4; ++a) ga[a] = Z4;
        stageChunks(WP_G1, 4, L_WB0);
        __syncthreads();
        #pragma unroll 1
        for (int kb = 0; kb < 10; ++kb){
            if (kb < 9)
                stageChunks(WP_G1 + (long)(kb + 1)*4096, 4, ((kb + 1) & 1) ? L_WB1 : L_WB0);
            int wb = (kb & 1) ? L_WB1 : L_WB0;
            bf16x8 b = loadB(wb, wc);
            #pragma unroll
            for (int mt = 0; mt < 4; ++mt){
                FragU a; a.u4 = *(const uint4*)(sm + L_XIN + kb*CHUNK + aoff[mt]);
                ga[mt] = mfma16(a.v, b, ga[mt]);
            }
            __syncthreads();
        }
        {   // h_g1 -> HG (cols 0..63)
            int n = wc*16 + l15;
            float bias = gb1[n];
            #pragma unroll
            for (int mt = 0; mt < 4; ++mt){
                f32x4 v;
                #pragma unroll
                for (int j = 0; j < 4; ++j) v[j] = eluf(ga[mt][j] + bias);
                putRow(L_HG, n, mt, v);
            }
        }
        __syncthreads();
        // ---- G2 ----
        stageChunks(WP_G2, 8, L_WB0);
        __syncthreads();
        #pragma unroll
        for (int a = 0; a < 4; ++a) ga[a] = Z4;
        #pragma unroll
        for (int kb = 0; kb < 2; ++kb){
            bf16x8 b = loadB(L_WB0, kb*4 + wc);
            #pragma unroll
            for (int mt = 0; mt < 4; ++mt){
                FragU a; a.u4 = *(const uint4*)(sm + L_HG + kb*CHUNK + aoff[mt]);
                ga[mt] = mfma16(a.v, b, ga[mt]);
            }
        }
        __syncthreads();
        {   // h_g2 -> HG2 (= WB1; HG dead after this)
            int n = wc*16 + l15;
            float bias = gb2[n];
            #pragma unroll
            for (int mt = 0; mt < 4; ++mt){
                f32x4 v;
                #pragma unroll
                for (int j = 0; j < 4; ++j) v[j] = eluf(ga[mt][j] + bias);
                putRow(L_HG2, n, mt, v);
            }
        }
        __syncthreads();
        // ---- G3 (N=16; waves with wc==0 handle their row half) ----
        stageChunks(WP_G3, 2, L_WB0);
        __syncthreads();
        if (wc == 0){
            f32x4 sc[4];
            #pragma unroll
            for (int a = 0; a < 4; ++a) sc[a] = Z4;
            #pragma unroll
            for (int kb = 0; kb < 2; ++kb){
                bf16x8 b = loadB(L_WB0, kb);
                #pragma unroll
                for (int mt = 0; mt < 4; ++mt){
                    FragU a; a.u4 = *(const uint4*)(sm + L_HG2 + kb*CHUNK + aoff[mt]);
                    sc[mt] = mfma16(a.v, b, sc[mt]);
                }
            }
            float bias = (l15 < 6) ? gb3[l15] : 0.f;
            #pragma unroll
            for (int mt = 0; mt < 4; ++mt)
                #pragma unroll
                for (int j = 0; j < 4; ++j){
                    int r = (wr << 6) + (mt << 4) + (lh << 2) + j;
                    *(float*)(sm + L_SCORE + (r << 6) + (l15 << 2)) = sc[mt][j] + bias;
                }
        }
        __syncthreads();
        if (tid < 128){
            float s[6];
            #pragma unroll
            for (int e = 0; e < 6; ++e) s[e] = *(const float*)(sm + L_SCORE + (tid << 6) + (e << 2));
            float m = s[0];
            #pragma unroll
            for (int e = 1; e < 6; ++e) m = fmaxf(m, s[e]);
            float sum = 0.f;
            #pragma unroll
            for (int e = 0; e < 6; ++e){ s[e] = expf(s[e] - m); sum += s[e]; }
            float inv = 1.f / sum;
            #pragma unroll
            for (int e = 0; e < 6; ++e) *(float*)(sm + L_COEF + ((e*128 + tid) << 2)) = s[e]*inv;
        }
        __syncthreads();
    }
    // ================= decoder: 4 MoE layers ================================
    // master carries the residual across layers AND is the MFMA accumulator
    // (LN scale folded into weights; LN shift folded into bdec; per-row
    //  coef*rstd folded into the A fragment).
    f32x4 master[4][4];
    #pragma unroll
    for (int a = 0; a < 4; ++a)
        #pragma unroll
        for (int b = 0; b < 4; ++b) master[a][b] = Z4;

    #pragma unroll 1
    for (int L = 0; L < 4; ++L){
        // ---- LN stats over the 320 raw bf16 values per row ----
        {
            int row = tid >> 2, part = tid & 3;
            float s = 0.f, q = 0.f;
            int sw = (row >> 1) & 3;
            #pragma unroll
            for (int c = 0; c < 10; ++c){
                uint4 d = *(const uint4*)(sm + L_XIN + c*CHUNK + (row << 6) + ((part ^ sw) << 4));
                const unsigned int* dw = (const unsigned int*)&d;
                #pragma unroll
                for (int u = 0; u < 4; ++u){
                    float lo = __uint_as_float(dw[u] << 16);
                    float hi = __uint_as_float(dw[u] & 0xffff0000u);
                    s += lo + hi; q += lo*lo + hi*hi;
                }
            }
            *(float2*)(sm + L_PART + (((row << 2) + part) << 3)) = make_float2(s, q);
        }
        __syncthreads();
        if (tid < 128){
            float S = 0.f, Q = 0.f;
            #pragma unroll
            for (int pp = 0; pp < 4; ++pp){
                float2 f = *(const float2*)(sm + L_PART + (((tid << 2) + pp) << 3));
                S += f.x; Q += f.y;
            }
            float mean = S * (1.f/320.f);
            float var  = Q * (1.f/320.f) - mean*mean;
            *(float2*)(sm + L_STATS + (tid << 3)) = make_float2(mean, rsqrtf(var + 1e-5f));
        }
        __syncthreads();
        float meanA[4], rstdA[4];
        #pragma unroll
        for (int mt = 0; mt < 4; ++mt){
            float2 st = *(const float2*)(sm + L_STATS + (((wr << 6) + (mt << 4) + l15) << 3));
            meanA[mt] = st.x; rstdA[mt] = st.y;
        }

        // ---- MoE loop: s = kb*6 + e; A-frags loaded once per kb, reused 6x
        long wbase = WP_DEC + (long)(L*6)*10*16384;
        stageChunks(wbase, 16, L_WB0);                 // (e=0, kb=0)
        __syncthreads();
        FragU araw[4];
        int e = 0, kb = 0;
        #pragma unroll 1
        for (int s = 0; s < 60; ++s){
            if (s < 59){
                int t = s + 1;
                int kbn = t / 6, en = t - kbn*6;
                stageChunks(wbase + (long)(en*10 + kbn)*16384, 16,
                            ((s + 1) & 1) ? L_WB1 : L_WB0);
            }
            if (e == 0){
                #pragma unroll
                for (int mt = 0; mt < 4; ++mt)
                    araw[mt].u4 = *(const uint4*)(sm + L_XIN + kb*CHUNK + aoff[mt]);
            }
            // a' = bf16( coef_e * (x - mean) * rstd )
            FragU as[4];
            #pragma unroll
            for (int mt = 0; mt < 4; ++mt){
                float c  = *(const float*)(sm + L_COEF +
                             ((e*128 + (wr << 6) + (mt << 4) + l15) << 2));
                float al = c * rstdA[mt];
                float be = -meanA[mt] * al;
                #pragma unroll
                for (int q = 0; q < 4; ++q){
                    unsigned int w = araw[mt].w[q];
                    float lo = fmaf(__uint_as_float(w << 16),          al, be);
                    float hi = fmaf(__uint_as_float(w & 0xffff0000u),  al, be);
                    as[mt].w[q] = pack2(lo, hi);
                }
            }
            int wb = (s & 1) ? L_WB1 : L_WB0;
            #pragma unroll
            for (int nt = 0; nt < 4; ++nt){
                FragU b; b.u4 = *(const uint4*)(sm + wb + ((wc*4 + nt) << 10) + (lane << 4));
                #pragma unroll
                for (int mt = 0; mt < 4; ++mt)
                    master[mt][nt] = mfma16(as[mt].v, b.v, master[mt][nt]);
            }
            __syncthreads();
            if (++e == 6){ e = 0; ++kb; }
        }

        // ---- epilogue: + blended bias, ELU, write back ----
        {
            float bv[6][4];
            #pragma unroll
            for (int ee = 0; ee < 6; ++ee)
                #pragma unroll
                for (int nt = 0; nt < 4; ++nt)
                    bv[ee][nt] = bdec[((L*6 + ee) << 8) + wc*64 + nt*16 + l15];
            #pragma unroll
            for (int mt = 0; mt < 4; ++mt){
                f32x4 cq[6];
                #pragma unroll
                for (int ee = 0; ee < 6; ++ee)
                    cq[ee] = *(const f32x4*)(sm + L_COEF +
                              ((ee*128 + (wr << 6) + (mt << 4) + (lh << 2)) << 2));
                #pragma unroll
                for (int nt = 0; nt < 4; ++nt){
                    int n = wc*64 + nt*16 + l15;
                    f32x4 v;
                    #pragma unroll
                    for (int j = 0; j < 4; ++j){
                        float bias = cq[0][j]*bv[0][nt] + cq[1][j]*bv[1][nt]
                                   + cq[2][j]*bv[2][nt] + cq[3][j]*bv[3][nt]
                                   + cq[4][j]*bv[4][nt] + cq[5][j]*bv[5][nt];
                        float mix = master[mt][nt][j] + bias;
                        v[j] = (L == 3) ? mix : eluf(mix);
                    }
                    if (L < 3){
                        master[mt][nt] = (L < 2) ? v : Z4;   // residual for next layer
                        putRow(L_XIN + 2*CHUNK, n, mt, v);   // raw out -> chunks 2..9
                    } else {
                        #pragma unroll
                        for (int j = 0; j < 4; ++j){
                            int r = (wr << 6) + (mt << 4) + (lh << 2) + j;
                            dout[(row0 + r)*256 + n] = v[j];
                        }
                    }
                }
            }
        }
        __syncthreads();
    }
}

// ---------------------------------------------------------------------------
extern "C" void kernel_launch(void* const* d_in, const int* in_sizes, int n_in,
                              void* d_out, int out_size, void* d_ws, size_t ws_size,
                              hipStream_t stream)
{
    (void)in_sizes; (void)n_in; (void)out_size; (void)ws_size;
    const float* curr = (const float*)d_in[0];
    const float* nxt  = (const float*)d_in[1];
    const float* eps  = (const float*)d_in[2];
    const float* ew1  = (const float*)d_in[3];
    const float* eb1  = (const float*)d_in[4];
    const float* ew2  = (const float*)d_in[5];
    const float* eb2  = (const float*)d_in[6];
    const float* muw  = (const float*)d_in[7];
    const float* mub  = (const float*)d_in[8];
    const float* lvw  = (const float*)d_in[9];
    const float* lvb  = (const float*)d_in[10];
    const float* gw1  = (const float*)d_in[11];
    const float* gb1  = (const float*)d_in[12];
    const float* gw2  = (const float*)d_in[13];
    const float* gb2  = (const float*)d_in[14];
    const float* gw3  = (const float*)d_in[15];
    const float* gb3  = (const float*)d_in[16];
    const float* w0 = (const float*)d_in[17]; const float* b0 = (const float*)d_in[18];
    const float* s0 = (const float*)d_in[19]; const float* t0 = (const float*)d_in[20];
    const float* w1 = (const float*)d_in[21]; const float* b1 = (const float*)d_in[22];
    const float* s1 = (const float*)d_in[23]; const float* t1 = (const float*)d_in[24];
    const float* w2 = (const float*)d_in[25]; const float* b2 = (const float*)d_in[26];
    const float* s2 = (const float*)d_in[27]; const float* t2 = (const float*)d_in[28];
    const float* w3 = (const float*)d_in[29]; const float* b3 = (const float*)d_in[30];
    const float* s3 = (const float*)d_in[31]; const float* t3 = (const float*)d_in[32];

    unsigned short* wsh = (unsigned short*)d_ws;
    float* bdec = (float*)((char*)d_ws + WP_BDEC);
    float* dout = (float*)d_out;

    hipLaunchKernelGGL(pack_small, dim3(996), dim3(256), 0, stream,
                       ew1, ew2, muw, lvw, gw1, gw2, gw3, wsh);
    hipLaunchKernelGGL(pack_dec, dim3(7680), dim3(256), 0, stream,
                       w0, w1, w2, w3, s0, s1, s2, s3, wsh);
    hipLaunchKernelGGL(pack_bdec, dim3(24), dim3(256), 0, stream,
                       w0, w1, w2, w3, b0, b1, b2, b3, t0, t1, t2, t3, bdec);
    hipLaunchKernelGGL(vae_main, dim3(512), dim3(512), 0, stream,
                       curr, nxt, eps, eb1, eb2, mub, lvb, gb1, gb2, gb3,
                       wsh, bdec, dout);
}